// Round 2
// 321.400 us; speedup vs baseline: 1.0613x; 1.0613x over previous
//
#include <hip/hip_runtime.h>

// B=4, S=2048, D=1024, H=16, head_dim=64. Inputs fp32, output fp32.
// MFMA bf16 pipeline; fp32 accumulate. 2-pass split-bf16 for Q/K projections.
// Round 11: T12 in-register softmax — swapped QK^T (mfma(K,Q)) so each lane owns a
// P-column; P goes reg->reg via v_cvt_pk_bf16_f32 + permlane32_swap (Ps LDS removed).
// Mask moved out of the inner loop: K/V masked rows zeroed in QKV epilogue (p=1 exactly
// for masked keys), denominator corrected by per-batch masked count; LOG2E folded into Q.
// Round 12: fix -Wc++11-narrowing on permlane32_swap results (uint -> int casts).
// ws (64MB): Xh[16] | Qb/ctx[16] | Kb[16] | Vt[16]  (Wo^T overlays Xh after its death)
// d_out (32MB) pre-final scratch: Xl[16] | Wcat[6] | mnorm[32KB] | bcat[12KB] | cnt[4]

#define Bb 4
#define Ss 2048
#define Dd 1024
#define Hh 16
#define SZt 8388608

typedef short bf16x8 __attribute__((ext_vector_type(8)));
typedef float f32x4 __attribute__((ext_vector_type(4)));
typedef float f32x16 __attribute__((ext_vector_type(16)));
typedef unsigned int u32x4 __attribute__((ext_vector_type(4)));
typedef unsigned short u16;

__device__ __forceinline__ float bf2f(u16 u) {
    return __builtin_bit_cast(float, ((unsigned)u) << 16);
}
__device__ __forceinline__ u16 f2bf(float f) {
    unsigned u = __builtin_bit_cast(unsigned, f);
    unsigned r = 0x7FFFu + ((u >> 16) & 1u);
    return (u16)((u + r) >> 16);
}
__device__ __forceinline__ bf16x8 ldfrag(const u16* p) {
    return __builtin_bit_cast(bf16x8, *(const uint4*)p);
}
__device__ __forceinline__ f32x4 mfma16(bf16x8 a, bf16x8 b, f32x4 c) {
    return __builtin_amdgcn_mfma_f32_16x16x32_bf16(a, b, c, 0, 0, 0);
}
__device__ __forceinline__ f32x16 mfma32(bf16x8 a, bf16x8 b, f32x16 c) {
    return __builtin_amdgcn_mfma_f32_32x32x16_bf16(a, b, c, 0, 0, 0);
}
// pack two f32 -> one u32 of 2x bf16 (lo=a, hi=b); no builtin on gfx950 (T12 recipe)
__device__ __forceinline__ unsigned cvt_pk_bf16(float a, float b) {
    unsigned r;
    asm("v_cvt_pk_bf16_f32 %0, %1, %2" : "=v"(r) : "v"(a), "v"(b));
    return r;
}
// async global->LDS, 16B/lane; LDS dest = wave-uniform base + lane*16 (m97 contract)
__device__ __forceinline__ void gl2lds16(const u16* g, u16* l) {
    __builtin_amdgcn_global_load_lds(
        (const __attribute__((address_space(1))) u16*)g,
        (__attribute__((address_space(3))) u16*)l, 16, 0, 0);
}

// ---------------- mask normalization -> mnorm (0/1 float) + per-batch masked count ----------------
__global__ void normalize_mask(const unsigned char* __restrict__ raw, float* __restrict__ out,
                               float* __restrict__ cnt, int n) {
    __shared__ int flags;
    __shared__ float scnt[Bb];
    if (threadIdx.x == 0) flags = 0;
    if (threadIdx.x < Bb) scnt[threadIdx.x] = 0.f;
    __syncthreads();
    int f = 0;
    for (int i = threadIdx.x; i < n; i += blockDim.x) {
        unsigned char c = raw[i];
        if ((i & 3) != 0 && c) f |= 1;
        if ((i & 3) == 1 && c >= 2) f |= 2;
        if ((i & 3) == 3 && c >= 2) f |= 4;
    }
    if (f) atomicOr(&flags, f);
    __syncthreads();
    int fl = flags;
    int layout;                 // 0=int32, 1=u8, 2=bf16, 3=f32
    if (!(fl & 1)) layout = 0;
    else if (fl & 2) layout = 2;
    else if (fl & 4) layout = 3;
    else layout = 1;
    for (int i = threadIdx.x; i < n; i += blockDim.x) {
        int v;
        if (layout == 0)      v = ((const int*)raw)[i];
        else if (layout == 1) v = raw[i];
        else if (layout == 2) v = ((const u16*)raw)[i] != 0;
        else                  v = ((const unsigned*)raw)[i] != 0;
        out[i] = (v != 0) ? 1.0f : 0.0f;
        if (v == 0) atomicAdd(&scnt[i >> 11], 1.0f);   // i>>11 = batch index (S=2048)
    }
    __syncthreads();
    if (threadIdx.x < Bb) cnt[threadIdx.x] = scnt[threadIdx.x];
}

// ---------------- bias concat [bq|bk|bv] -> bcat[3072] ----------------
__global__ void concat_bias(const float* __restrict__ a, const float* __restrict__ b,
                            const float* __restrict__ c, float* __restrict__ o) {
    int i = blockIdx.x * 256 + threadIdx.x;
    o[i] = (i < 1024) ? a[i] : ((i < 2048) ? b[i - 1024] : c[i - 2048]);
}

// ---------------- X fp32 -> hi/lo bf16 split ----------------
__global__ __launch_bounds__(256) void convert_x(const float* __restrict__ X,
                                                 u16* __restrict__ Xh, u16* __restrict__ Xl) {
    size_t i = ((size_t)blockIdx.x * 256 + threadIdx.x) * 4;
    float4 v = *(const float4*)(X + i);
    u16 h0 = f2bf(v.x), h1 = f2bf(v.y), h2 = f2bf(v.z), h3 = f2bf(v.w);
    u16 l0 = f2bf(v.x - bf2f(h0)), l1 = f2bf(v.y - bf2f(h1));
    u16 l2 = f2bf(v.z - bf2f(h2)), l3 = f2bf(v.w - bf2f(h3));
    uint2 ph = { (unsigned)h0 | ((unsigned)h1 << 16), (unsigned)h2 | ((unsigned)h3 << 16) };
    uint2 pl = { (unsigned)l0 | ((unsigned)l1 << 16), (unsigned)l2 | ((unsigned)l3 << 16) };
    *(uint2*)(Xh + i) = ph;
    *(uint2*)(Xl + i) = pl;
}

// ---------------- W [K][N] fp32 -> Wt [N][K] bf16 (tiled transpose) ----------------
__global__ __launch_bounds__(256) void transpose_w(const float* __restrict__ W, u16* __restrict__ Wt) {
    __shared__ float t[32][33];
    const int tx = threadIdx.x, ty = threadIdx.y;
    const int n0 = blockIdx.x * 32, k0 = blockIdx.y * 32;
    #pragma unroll
    for (int i = 0; i < 4; i++)
        t[ty + i * 8][tx] = W[(size_t)(k0 + ty + i * 8) * Dd + n0 + tx];
    __syncthreads();
    #pragma unroll
    for (int i = 0; i < 4; i++)
        Wt[(size_t)(n0 + ty + i * 8) * Dd + k0 + tx] = f2bf(t[tx][ty + i * 8]);
}

// ---------------- fused QKV GEMM: [Q|K|V][8192,1024] = X[8192,1024] @ Wcat^T + bcat ----------------
// Epilogue: Q scaled by LOG2E (log2-domain scores); K,V rows multiplied by key mask (0/1).
__global__ __launch_bounds__(256) void gemm_qkv(
    const u16* __restrict__ Ah, const u16* __restrict__ Al,
    const u16* __restrict__ Wcat, const float* __restrict__ bcat,
    const float* __restrict__ mnorm,
    u16* __restrict__ Qb, u16* __restrict__ Kb, u16* __restrict__ Vt)
{
    __shared__ u16 Ahs[128][64];
    __shared__ u16 Bs[128][64];
    __shared__ u16 Als[128][64];
    const int tid = threadIdx.x, lane = tid & 63, wave = tid >> 6;
    const int wm = wave >> 1, wn = wave & 1;
    const int bm = blockIdx.y * 128, bn = blockIdx.x * 128;
    const bool twopass = (bn < 2048);
    const bool isQ = (bn < 1024);
    const int l15 = lane & 15, lq = lane >> 4;
    const int sr = wave * 32 + (lane >> 3);
    const int sc = (lane & 7) * 8;
    const u16* agp = Ah + (size_t)(bm + sr) * Dd + sc;
    const u16* bgp = Wcat + (size_t)(bn + sr) * Dd + sc;
    const u16* algp = Al + (size_t)(bm + sr) * Dd + sc;

    f32x4 acc[4][4] = {};

    for (int k0 = 0; k0 < Dd; k0 += 64) {
        __syncthreads();
        #pragma unroll
        for (int j = 0; j < 4; j++) {
            gl2lds16(agp + k0 + (size_t)j * 8 * Dd, &Ahs[wave * 32 + j * 8][0]);
            gl2lds16(bgp + k0 + (size_t)j * 8 * Dd, &Bs[wave * 32 + j * 8][0]);
            if (twopass)
                gl2lds16(algp + k0 + (size_t)j * 8 * Dd, &Als[wave * 32 + j * 8][0]);
        }
        __syncthreads();
        #pragma unroll
        for (int kf = 0; kf < 2; kf++) {
            bf16x8 b[4], a[4];
            #pragma unroll
            for (int nt = 0; nt < 4; nt++)
                b[nt] = ldfrag(&Bs[wn * 64 + nt * 16 + l15][kf * 32 + lq * 8]);
            #pragma unroll
            for (int mt = 0; mt < 4; mt++)
                a[mt] = ldfrag(&Ahs[wm * 64 + mt * 16 + l15][kf * 32 + lq * 8]);
            #pragma unroll
            for (int mt = 0; mt < 4; mt++)
                #pragma unroll
                for (int nt = 0; nt < 4; nt++)
                    acc[mt][nt] = mfma16(a[mt], b[nt], acc[mt][nt]);
            if (twopass) {
                bf16x8 al2[4];
                #pragma unroll
                for (int mt = 0; mt < 4; mt++)
                    al2[mt] = ldfrag(&Als[wm * 64 + mt * 16 + l15][kf * 32 + lq * 8]);
                #pragma unroll
                for (int mt = 0; mt < 4; mt++)
                    #pragma unroll
                    for (int nt = 0; nt < 4; nt++)
                        acc[mt][nt] = mfma16(al2[mt], b[nt], acc[mt][nt]);
            }
        }
    }
    const float LOG2E = 1.44269504088896f;
    float bv[4];
    #pragma unroll
    for (int nt = 0; nt < 4; nt++) bv[nt] = bcat[bn + wn * 64 + nt * 16 + l15];
    #pragma unroll
    for (int mt = 0; mt < 4; mt++) {
        int r0 = bm + wm * 64 + mt * 16 + lq * 4;
        float mk[4];
        if (!isQ) {
            #pragma unroll
            for (int rr = 0; rr < 4; rr++) mk[rr] = mnorm[r0 + rr];
        }
        #pragma unroll
        for (int nt = 0; nt < 4; nt++) {
            int col = bn + wn * 64 + nt * 16 + l15;
            if (col < 1024) {                                  // Q (pre-scaled by log2e)
                #pragma unroll
                for (int rr = 0; rr < 4; rr++)
                    Qb[(size_t)(r0 + rr) * Dd + col] = f2bf((acc[mt][nt][rr] + bv[nt]) * LOG2E);
            } else if (col < 2048) {                           // K (masked rows -> 0)
                int c2 = col - 1024;
                #pragma unroll
                for (int rr = 0; rr < 4; rr++)
                    Kb[(size_t)(r0 + rr) * Dd + c2] = f2bf((acc[mt][nt][rr] + bv[nt]) * mk[rr]);
            } else {                                           // V, transposed [b][h][d][s], masked
                int c2 = col - 2048;
                int hh = c2 >> 6, dd = c2 & 63, b_ = r0 >> 11, s0 = r0 & 2047;
                u16 e0 = f2bf((acc[mt][nt][0] + bv[nt]) * mk[0]);
                u16 e1 = f2bf((acc[mt][nt][1] + bv[nt]) * mk[1]);
                u16 e2 = f2bf((acc[mt][nt][2] + bv[nt]) * mk[2]);
                u16 e3 = f2bf((acc[mt][nt][3] + bv[nt]) * mk[3]);
                uint2 pk = { (unsigned)e0 | ((unsigned)e1 << 16), (unsigned)e2 | ((unsigned)e3 << 16) };
                *(uint2*)(Vt + (size_t)((b_ * Hh + hh) * 64 + dd) * Ss + s0) = pk;
            }
        }
    }
}

// ---------------- m97-style GEMM (output projection): fp32 out ----------------
__global__ __launch_bounds__(256) void gemm_out(
    const u16* __restrict__ Ah, const u16* __restrict__ Wt,
    const float* __restrict__ bias, float* __restrict__ Cout)
{
    __shared__ u16 Ahs[128][64];
    __shared__ u16 Bs[128][64];
    const int tid = threadIdx.x, lane = tid & 63, wave = tid >> 6;
    const int wm = wave >> 1, wn = wave & 1;
    const int bm = blockIdx.y * 128, bn = blockIdx.x * 128;
    const int l15 = lane & 15, lq = lane >> 4;
    const int sr = wave * 32 + (lane >> 3);
    const int sc = (lane & 7) * 8;
    const u16* agp = Ah + (size_t)(bm + sr) * Dd + sc;
    const u16* bgp = Wt + (size_t)(bn + sr) * Dd + sc;

    f32x4 acc[4][4] = {};

    for (int k0 = 0; k0 < Dd; k0 += 64) {
        __syncthreads();
        #pragma unroll
        for (int j = 0; j < 4; j++) {
            gl2lds16(agp + k0 + (size_t)j * 8 * Dd, &Ahs[wave * 32 + j * 8][0]);
            gl2lds16(bgp + k0 + (size_t)j * 8 * Dd, &Bs[wave * 32 + j * 8][0]);
        }
        __syncthreads();
        #pragma unroll
        for (int kf = 0; kf < 2; kf++) {
            bf16x8 b[4], a[4];
            #pragma unroll
            for (int nt = 0; nt < 4; nt++)
                b[nt] = ldfrag(&Bs[wn * 64 + nt * 16 + l15][kf * 32 + lq * 8]);
            #pragma unroll
            for (int mt = 0; mt < 4; mt++)
                a[mt] = ldfrag(&Ahs[wm * 64 + mt * 16 + l15][kf * 32 + lq * 8]);
            #pragma unroll
            for (int mt = 0; mt < 4; mt++)
                #pragma unroll
                for (int nt = 0; nt < 4; nt++)
                    acc[mt][nt] = mfma16(a[mt], b[nt], acc[mt][nt]);
        }
    }
    float bv[4];
    #pragma unroll
    for (int nt = 0; nt < 4; nt++) bv[nt] = bias[bn + wn * 64 + nt * 16 + l15];
    #pragma unroll
    for (int mt = 0; mt < 4; mt++) {
        int r0 = bm + wm * 64 + mt * 16 + lq * 4;
        #pragma unroll
        for (int nt = 0; nt < 4; nt++) {
            int col = bn + wn * 64 + nt * 16 + l15;
            #pragma unroll
            for (int rr = 0; rr < 4; rr++)
                Cout[(size_t)(r0 + rr) * Dd + col] = acc[mt][nt][rr] + bv[nt];
        }
    }
}

// ---------------- MFMA flash attention v6: swapped QK^T, in-register P (T12) ----------------
// grid (B*H, S/256), XCD-swizzled (bh fast). 512 thr = 8 waves; wave owns 32 q-rows.
// sc = mfma32(K, Q) -> lane holds S^T column (one q, 16 keys crow(r,hi) per half-wave).
// p = exp2(sc) (Q pre-scaled by log2e; masked keys give p=1 exactly, subtracted via cnt[b]).
// P -> bf16 A-fragments via cvt_pk + permlane32_swap; no Ps LDS, no lgkm wait before PV.
__global__ __launch_bounds__(512, 4) void attn_mfma(
    u16* qctx, const u16* __restrict__ Kb, const u16* __restrict__ Vt,
    const float* __restrict__ maskf, const float* __restrict__ cntp)
{
    __shared__ u16 Ks[64][72];       // [key][d]   (144B rows: 16B-aligned)
    __shared__ u16 Vs[64][72];       // [d][key]
    __shared__ float li_s[8][32];    // per-wave li broadcast (epilogue only)
    const int tid = threadIdx.x, lane = tid & 63, wave = tid >> 6;
    const int l31 = lane & 31, hi = lane >> 5;
    const int bh = blockIdx.x, h = bh & 15, b = bh >> 4;
    const int q0 = blockIdx.y * 256;

    bf16x8 qa[4];
    {
        const u16* qp = qctx + (size_t)(b * Ss + q0 + wave * 32 + l31) * Dd + h * 64 + hi * 8;
        #pragma unroll
        for (int kf = 0; kf < 4; kf++) qa[kf] = ldfrag(qp + kf * 16);
    }

    const int srow = tid >> 3, scol = (tid & 7) * 8;
    const u16* kgsrc = Kb + (size_t)(b * Ss + srow) * Dd + h * 64 + scol;
    const u16* vgsrc = Vt + (size_t)((b * Hh + h) * 64 + srow) * Ss + scol;
    u16* kdst = &Ks[srow][scol];
    u16* vdst = &Vs[srow][scol];

    f32x16 acc0 = {}, acc1 = {};
    float li = 0.f;

    uint4 kreg = *(const uint4*)kgsrc;
    uint4 vreg = *(const uint4*)vgsrc;

    for (int k0 = 0; k0 < Ss; k0 += 64) {
        __syncthreads();
        *(uint4*)kdst = kreg;
        *(uint4*)vdst = vreg;
        __syncthreads();
        int k0n = (k0 + 64 < Ss) ? k0 + 64 : 0;
        kreg = *(const uint4*)(kgsrc + (size_t)k0n * Dd);
        vreg = *(const uint4*)(vgsrc + k0n);

        #pragma unroll
        for (int nt = 0; nt < 2; nt++) {
            // QK^T swapped: A=K rows (32 keys), B=Q cols (32 q). Lane: q=l31, key=crow(r,hi).
            f32x16 sc = {};
            #pragma unroll
            for (int kf = 0; kf < 4; kf++) {
                bf16x8 kb = ldfrag(&Ks[nt * 32 + l31][kf * 16 + hi * 8]);
                sc = mfma32(kb, qa[kf], sc);
            }
            // keys 0..15 of this half -> pa0 -> PV kf=0
            float p[16];
            #pragma unroll
            for (int r = 0; r < 8; r++) p[r] = __builtin_amdgcn_exp2f(sc[r]);
            li += ((p[0] + p[1]) + (p[2] + p[3])) + ((p[4] + p[5]) + (p[6] + p[7]));
            {
                unsigned w0 = cvt_pk_bf16(p[0], p[1]), w1 = cvt_pk_bf16(p[2], p[3]);
                unsigned w2 = cvt_pk_bf16(p[4], p[5]), w3 = cvt_pk_bf16(p[6], p[7]);
                auto s02 = __builtin_amdgcn_permlane32_swap((int)w0, (int)w2, false, false);
                auto s13 = __builtin_amdgcn_permlane32_swap((int)w1, (int)w3, false, false);
                u32x4 pw = { (unsigned)s02[0], (unsigned)s13[0], (unsigned)s02[1], (unsigned)s13[1] };
                bf16x8 pa0 = __builtin_bit_cast(bf16x8, pw);
                bf16x8 v00 = ldfrag(&Vs[l31][nt * 32 + hi * 8]);
                bf16x8 v10 = ldfrag(&Vs[32 + l31][nt * 32 + hi * 8]);
                acc0 = mfma32(pa0, v00, acc0);
                acc1 = mfma32(pa0, v10, acc1);
            }
            // keys 16..31 -> pa1 -> PV kf=1
            #pragma unroll
            for (int r = 8; r < 16; r++) p[r] = __builtin_amdgcn_exp2f(sc[r]);
            li += ((p[8] + p[9]) + (p[10] + p[11])) + ((p[12] + p[13]) + (p[14] + p[15]));
            {
                unsigned w4 = cvt_pk_bf16(p[8], p[9]),  w5 = cvt_pk_bf16(p[10], p[11]);
                unsigned w6 = cvt_pk_bf16(p[12], p[13]), w7 = cvt_pk_bf16(p[14], p[15]);
                auto s46 = __builtin_amdgcn_permlane32_swap((int)w4, (int)w6, false, false);
                auto s57 = __builtin_amdgcn_permlane32_swap((int)w5, (int)w7, false, false);
                u32x4 pw = { (unsigned)s46[0], (unsigned)s57[0], (unsigned)s46[1], (unsigned)s57[1] };
                bf16x8 pa1 = __builtin_bit_cast(bf16x8, pw);
                bf16x8 v01 = ldfrag(&Vs[l31][nt * 32 + 16 + hi * 8]);
                bf16x8 v11 = ldfrag(&Vs[32 + l31][nt * 32 + 16 + hi * 8]);
                acc0 = mfma32(pa1, v01, acc0);
                acc1 = mfma32(pa1, v11, acc1);
            }
        }
    }

    // li is per-q (q = l31); combine complementary key-halves, broadcast to row lanes.
    float li_tot = li + __shfl_xor(li, 32);
    if (hi == 0) li_s[wave][l31] = li_tot;
    __builtin_amdgcn_s_barrier();
    float cntb = cntp[b];
    #pragma unroll
    for (int g = 0; g < 4; g++) {
        float4 lv = *(const float4*)&li_s[wave][g * 8 + hi * 4];
        #pragma unroll
        for (int j = 0; j < 4; j++) {
            int r = g * 4 + j;
            int row = j + 8 * g + 4 * hi;
            int q = q0 + wave * 32 + row;
            float qm = maskf[b * Ss + q];
            float den = lv[j] - cntb;                 // subtract masked keys' exact 1.0s
            float rl = den > 0.f ? qm / den : 0.f;
            u16* op = qctx + (size_t)(b * Ss + q) * Dd + h * 64 + l31;
            op[0]  = f2bf(acc0[r] * rl);
            op[32] = f2bf(acc1[r] * rl);
        }
    }
}

extern "C" void kernel_launch(void* const* d_in, const int* in_sizes, int n_in,
                              void* d_out, int out_size, void* d_ws, size_t ws_size,
                              hipStream_t stream) {
    const float* X  = (const float*)d_in[0];
    const unsigned char* mr = (const unsigned char*)d_in[1];
    const float* Wq = (const float*)d_in[2];
    const float* bq = (const float*)d_in[3];
    const float* Wk = (const float*)d_in[4];
    const float* bk = (const float*)d_in[5];
    const float* Wv = (const float*)d_in[6];
    const float* bv = (const float*)d_in[7];
    const float* Wo = (const float*)d_in[8];
    const float* bo = (const float*)d_in[9];
    float* out = (float*)d_out;

    // ws (64 MB)
    u16* wsb = (u16*)d_ws;
    u16* Xh  = wsb;                // dies after QKV-gemm; Wo^T overlays
    u16* Qb  = wsb + (size_t)SZt;  // ctx aliases after attention
    u16* Kb  = wsb + 2 * (size_t)SZt;
    u16* Vt  = wsb + 3 * (size_t)SZt;
    u16* Wot = Xh;
    // d_out scratch (first ~22.1 MB; all dead before gemm_out writes d_out)
    u16* ob  = (u16*)d_out;
    u16* Xl  = ob;
    u16* Wcat = ob + (size_t)SZt;              // Wqt|Wkt|Wvt contiguous = [3072][1024]
    u16* Wqt = Wcat;
    u16* Wkt = Wqt + 1048576;
    u16* Wvt = Wkt + 1048576;
    float* mnorm = (float*)(Wvt + 1048576);    // 32 KB
    float* bcat  = mnorm + Bb * Ss;            // 12 KB
    float* cntp  = bcat + 3072;                // 16 B (per-batch masked-key count)

    dim3 tg(32, 32), tb(32, 8);

    normalize_mask<<<1, 1024, 0, stream>>>(mr, mnorm, cntp, Bb * Ss);
    concat_bias<<<12, 256, 0, stream>>>(bq, bk, bv, bcat);
    convert_x<<<SZt / 1024, 256, 0, stream>>>(X, Xh, Xl);
    transpose_w<<<tg, tb, 0, stream>>>(Wq, Wqt);
    transpose_w<<<tg, tb, 0, stream>>>(Wk, Wkt);
    transpose_w<<<tg, tb, 0, stream>>>(Wv, Wvt);
    gemm_qkv<<<dim3(24, 64), 256, 0, stream>>>(Xh, Xl, Wcat, bcat, mnorm, Qb, Kb, Vt);
    transpose_w<<<tg, tb, 0, stream>>>(Wo, Wot);               // Xh dead -> reuse
    attn_mfma<<<dim3(Bb * Hh, Ss / 256), 512, 0, stream>>>(Qb, Kb, Vt, mnorm, cntp);
    gemm_out<<<dim3(8, 64), 256, 0, stream>>>(Qb, Wot, bo, out);
}

// Round 3
// 310.952 us; speedup vs baseline: 1.0969x; 1.0336x over previous
//
#include <hip/hip_runtime.h>

// B=4, S=2048, D=1024, H=16, head_dim=64. Inputs fp32, output fp32.
// Round 13: QKV projection GEMM switched to fp16 single-pass (was bf16 two-pass hi/lo).
// Rationale: fp16 dot error (~2^-11*sqrt(K)) is below the bf16 store quantization both
// variants share -> same final accuracy at 60% of the MFMA work and 2/3 the staging.
// Q/K stored fp16 (attn QK^T uses f16 MFMA); P/V stay bf16 (unshifted softmax needs
// bf16's exponent range: p up to ~2^50). T12 in-register softmax retained.
// ws (64MB): Xh[16] | Qb/ctx[16] | Kb[16] | Vt[16]  (Wo^T overlays Xh after its death)
// d_out (32MB) pre-final scratch: (unused)[16] | Wcat[6] | mnorm[32KB] | bcat[12KB] | cnt[4]

#define Bb 4
#define Ss 2048
#define Dd 1024
#define Hh 16
#define SZt 8388608

typedef short bf16x8 __attribute__((ext_vector_type(8)));
typedef _Float16 f16x8 __attribute__((ext_vector_type(8)));
typedef float f32x4 __attribute__((ext_vector_type(4)));
typedef float f32x16 __attribute__((ext_vector_type(16)));
typedef unsigned int u32x4 __attribute__((ext_vector_type(4)));
typedef unsigned short u16;

__device__ __forceinline__ float bf2f(u16 u) {
    return __builtin_bit_cast(float, ((unsigned)u) << 16);
}
__device__ __forceinline__ u16 f2bf(float f) {
    unsigned u = __builtin_bit_cast(unsigned, f);
    unsigned r = 0x7FFFu + ((u >> 16) & 1u);
    return (u16)((u + r) >> 16);
}
__device__ __forceinline__ u16 f2h(float f) {
    _Float16 h = (_Float16)f;
    return __builtin_bit_cast(u16, h);
}
__device__ __forceinline__ bf16x8 ldfrag(const u16* p) {
    return __builtin_bit_cast(bf16x8, *(const uint4*)p);
}
__device__ __forceinline__ f16x8 ldfragh(const u16* p) {
    return __builtin_bit_cast(f16x8, *(const uint4*)p);
}
__device__ __forceinline__ f32x4 mfma16h(f16x8 a, f16x8 b, f32x4 c) {
    return __builtin_amdgcn_mfma_f32_16x16x32_f16(a, b, c, 0, 0, 0);
}
__device__ __forceinline__ f32x16 mfma32(bf16x8 a, bf16x8 b, f32x16 c) {
    return __builtin_amdgcn_mfma_f32_32x32x16_bf16(a, b, c, 0, 0, 0);
}
__device__ __forceinline__ f32x16 mfma32h(f16x8 a, f16x8 b, f32x16 c) {
    return __builtin_amdgcn_mfma_f32_32x32x16_f16(a, b, c, 0, 0, 0);
}
// pack two f32 -> one u32 of 2x bf16 (lo=a, hi=b); no builtin on gfx950 (T12 recipe)
__device__ __forceinline__ unsigned cvt_pk_bf16(float a, float b) {
    unsigned r;
    asm("v_cvt_pk_bf16_f32 %0, %1, %2" : "=v"(r) : "v"(a), "v"(b));
    return r;
}
// async global->LDS, 16B/lane; LDS dest = wave-uniform base + lane*16 (m97 contract)
__device__ __forceinline__ void gl2lds16(const u16* g, u16* l) {
    __builtin_amdgcn_global_load_lds(
        (const __attribute__((address_space(1))) u16*)g,
        (__attribute__((address_space(3))) u16*)l, 16, 0, 0);
}

// ---------------- mask normalization -> mnorm (0/1 float) + per-batch masked count ----------------
__global__ void normalize_mask(const unsigned char* __restrict__ raw, float* __restrict__ out,
                               float* __restrict__ cnt, int n) {
    __shared__ int flags;
    __shared__ float scnt[Bb];
    if (threadIdx.x == 0) flags = 0;
    if (threadIdx.x < Bb) scnt[threadIdx.x] = 0.f;
    __syncthreads();
    int f = 0;
    for (int i = threadIdx.x; i < n; i += blockDim.x) {
        unsigned char c = raw[i];
        if ((i & 3) != 0 && c) f |= 1;
        if ((i & 3) == 1 && c >= 2) f |= 2;
        if ((i & 3) == 3 && c >= 2) f |= 4;
    }
    if (f) atomicOr(&flags, f);
    __syncthreads();
    int fl = flags;
    int layout;                 // 0=int32, 1=u8, 2=bf16, 3=f32
    if (!(fl & 1)) layout = 0;
    else if (fl & 2) layout = 2;
    else if (fl & 4) layout = 3;
    else layout = 1;
    for (int i = threadIdx.x; i < n; i += blockDim.x) {
        int v;
        if (layout == 0)      v = ((const int*)raw)[i];
        else if (layout == 1) v = raw[i];
        else if (layout == 2) v = ((const u16*)raw)[i] != 0;
        else                  v = ((const unsigned*)raw)[i] != 0;
        out[i] = (v != 0) ? 1.0f : 0.0f;
        if (v == 0) atomicAdd(&scnt[i >> 11], 1.0f);   // i>>11 = batch index (S=2048)
    }
    __syncthreads();
    if (threadIdx.x < Bb) cnt[threadIdx.x] = scnt[threadIdx.x];
}

// ---------------- bias concat [bq|bk|bv] -> bcat[3072] ----------------
__global__ void concat_bias(const float* __restrict__ a, const float* __restrict__ b,
                            const float* __restrict__ c, float* __restrict__ o) {
    int i = blockIdx.x * 256 + threadIdx.x;
    o[i] = (i < 1024) ? a[i] : ((i < 2048) ? b[i - 1024] : c[i - 2048]);
}

// ---------------- X fp32 -> fp16 ----------------
__global__ __launch_bounds__(256) void convert_xh(const float* __restrict__ X,
                                                  u16* __restrict__ Xh) {
    size_t i = ((size_t)blockIdx.x * 256 + threadIdx.x) * 4;
    float4 v = *(const float4*)(X + i);
    u16 h0 = f2h(v.x), h1 = f2h(v.y), h2 = f2h(v.z), h3 = f2h(v.w);
    uint2 ph = { (unsigned)h0 | ((unsigned)h1 << 16), (unsigned)h2 | ((unsigned)h3 << 16) };
    *(uint2*)(Xh + i) = ph;
}

// ---------------- W [K][N] fp32 -> Wt [N][K] (tiled transpose) ----------------
__global__ __launch_bounds__(256) void transpose_wh(const float* __restrict__ W, u16* __restrict__ Wt) {
    __shared__ float t[32][33];
    const int tx = threadIdx.x, ty = threadIdx.y;
    const int n0 = blockIdx.x * 32, k0 = blockIdx.y * 32;
    #pragma unroll
    for (int i = 0; i < 4; i++)
        t[ty + i * 8][tx] = W[(size_t)(k0 + ty + i * 8) * Dd + n0 + tx];
    __syncthreads();
    #pragma unroll
    for (int i = 0; i < 4; i++)
        Wt[(size_t)(n0 + ty + i * 8) * Dd + k0 + tx] = f2h(t[tx][ty + i * 8]);
}
__global__ __launch_bounds__(256) void transpose_w(const float* __restrict__ W, u16* __restrict__ Wt) {
    __shared__ float t[32][33];
    const int tx = threadIdx.x, ty = threadIdx.y;
    const int n0 = blockIdx.x * 32, k0 = blockIdx.y * 32;
    #pragma unroll
    for (int i = 0; i < 4; i++)
        t[ty + i * 8][tx] = W[(size_t)(k0 + ty + i * 8) * Dd + n0 + tx];
    __syncthreads();
    #pragma unroll
    for (int i = 0; i < 4; i++)
        Wt[(size_t)(n0 + ty + i * 8) * Dd + k0 + tx] = f2bf(t[tx][ty + i * 8]);
}

// ---------------- fused QKV GEMM (fp16, single pass): [Q|K|V][8192,1024] = X @ Wcat^T + bcat ----
// Epilogue: Q scaled by LOG2E, stored fp16; K masked, stored fp16; V masked, stored bf16 [b][h][d][s].
__global__ __launch_bounds__(256) void gemm_qkv(
    const u16* __restrict__ Ah, const u16* __restrict__ Wcat, const float* __restrict__ bcat,
    const float* __restrict__ mnorm,
    u16* __restrict__ Qb, u16* __restrict__ Kb, u16* __restrict__ Vt)
{
    __shared__ u16 Ahs[128][64];
    __shared__ u16 Bs[128][64];
    const int tid = threadIdx.x, lane = tid & 63, wave = tid >> 6;
    const int wm = wave >> 1, wn = wave & 1;
    const int bm = blockIdx.y * 128, bn = blockIdx.x * 128;
    const bool isQ = (bn < 1024);
    const int l15 = lane & 15, lq = lane >> 4;
    const int sr = wave * 32 + (lane >> 3);
    const int sc = (lane & 7) * 8;
    const u16* agp = Ah + (size_t)(bm + sr) * Dd + sc;
    const u16* bgp = Wcat + (size_t)(bn + sr) * Dd + sc;

    f32x4 acc[4][4] = {};

    for (int k0 = 0; k0 < Dd; k0 += 64) {
        __syncthreads();
        #pragma unroll
        for (int j = 0; j < 4; j++) {
            gl2lds16(agp + k0 + (size_t)j * 8 * Dd, &Ahs[wave * 32 + j * 8][0]);
            gl2lds16(bgp + k0 + (size_t)j * 8 * Dd, &Bs[wave * 32 + j * 8][0]);
        }
        __syncthreads();
        #pragma unroll
        for (int kf = 0; kf < 2; kf++) {
            f16x8 b[4], a[4];
            #pragma unroll
            for (int nt = 0; nt < 4; nt++)
                b[nt] = ldfragh(&Bs[wn * 64 + nt * 16 + l15][kf * 32 + lq * 8]);
            #pragma unroll
            for (int mt = 0; mt < 4; mt++)
                a[mt] = ldfragh(&Ahs[wm * 64 + mt * 16 + l15][kf * 32 + lq * 8]);
            #pragma unroll
            for (int mt = 0; mt < 4; mt++)
                #pragma unroll
                for (int nt = 0; nt < 4; nt++)
                    acc[mt][nt] = mfma16h(a[mt], b[nt], acc[mt][nt]);
        }
    }
    const float LOG2E = 1.44269504088896f;
    float bv[4];
    #pragma unroll
    for (int nt = 0; nt < 4; nt++) bv[nt] = bcat[bn + wn * 64 + nt * 16 + l15];
    #pragma unroll
    for (int mt = 0; mt < 4; mt++) {
        int r0 = bm + wm * 64 + mt * 16 + lq * 4;
        float mk[4];
        if (!isQ) {
            #pragma unroll
            for (int rr = 0; rr < 4; rr++) mk[rr] = mnorm[r0 + rr];
        }
        #pragma unroll
        for (int nt = 0; nt < 4; nt++) {
            int col = bn + wn * 64 + nt * 16 + l15;
            if (col < 1024) {                                  // Q fp16 (pre-scaled by log2e)
                #pragma unroll
                for (int rr = 0; rr < 4; rr++)
                    Qb[(size_t)(r0 + rr) * Dd + col] = f2h((acc[mt][nt][rr] + bv[nt]) * LOG2E);
            } else if (col < 2048) {                           // K fp16 (masked rows -> 0)
                int c2 = col - 1024;
                #pragma unroll
                for (int rr = 0; rr < 4; rr++)
                    Kb[(size_t)(r0 + rr) * Dd + c2] = f2h((acc[mt][nt][rr] + bv[nt]) * mk[rr]);
            } else {                                           // V bf16, transposed [b][h][d][s], masked
                int c2 = col - 2048;
                int hh = c2 >> 6, dd = c2 & 63, b_ = r0 >> 11, s0 = r0 & 2047;
                u16 e0 = f2bf((acc[mt][nt][0] + bv[nt]) * mk[0]);
                u16 e1 = f2bf((acc[mt][nt][1] + bv[nt]) * mk[1]);
                u16 e2 = f2bf((acc[mt][nt][2] + bv[nt]) * mk[2]);
                u16 e3 = f2bf((acc[mt][nt][3] + bv[nt]) * mk[3]);
                uint2 pk = { (unsigned)e0 | ((unsigned)e1 << 16), (unsigned)e2 | ((unsigned)e3 << 16) };
                *(uint2*)(Vt + (size_t)((b_ * Hh + hh) * 64 + dd) * Ss + s0) = pk;
            }
        }
    }
}

// ---------------- m97-style GEMM (output projection, bf16): fp32 out ----------------
__global__ __launch_bounds__(256) void gemm_out(
    const u16* __restrict__ Ah, const u16* __restrict__ Wt,
    const float* __restrict__ bias, float* __restrict__ Cout)
{
    __shared__ u16 Ahs[128][64];
    __shared__ u16 Bs[128][64];
    const int tid = threadIdx.x, lane = tid & 63, wave = tid >> 6;
    const int wm = wave >> 1, wn = wave & 1;
    const int bm = blockIdx.y * 128, bn = blockIdx.x * 128;
    const int l15 = lane & 15, lq = lane >> 4;
    const int sr = wave * 32 + (lane >> 3);
    const int sc = (lane & 7) * 8;
    const u16* agp = Ah + (size_t)(bm + sr) * Dd + sc;
    const u16* bgp = Wt + (size_t)(bn + sr) * Dd + sc;

    f32x4 acc[4][4] = {};

    for (int k0 = 0; k0 < Dd; k0 += 64) {
        __syncthreads();
        #pragma unroll
        for (int j = 0; j < 4; j++) {
            gl2lds16(agp + k0 + (size_t)j * 8 * Dd, &Ahs[wave * 32 + j * 8][0]);
            gl2lds16(bgp + k0 + (size_t)j * 8 * Dd, &Bs[wave * 32 + j * 8][0]);
        }
        __syncthreads();
        #pragma unroll
        for (int kf = 0; kf < 2; kf++) {
            bf16x8 b[4], a[4];
            #pragma unroll
            for (int nt = 0; nt < 4; nt++)
                b[nt] = ldfrag(&Bs[wn * 64 + nt * 16 + l15][kf * 32 + lq * 8]);
            #pragma unroll
            for (int mt = 0; mt < 4; mt++)
                a[mt] = ldfrag(&Ahs[wm * 64 + mt * 16 + l15][kf * 32 + lq * 8]);
            #pragma unroll
            for (int mt = 0; mt < 4; mt++)
                #pragma unroll
                for (int nt = 0; nt < 4; nt++)
                    acc[mt][nt] = __builtin_amdgcn_mfma_f32_16x16x32_bf16(a[mt], b[nt], acc[mt][nt], 0, 0, 0);
        }
    }
    float bv[4];
    #pragma unroll
    for (int nt = 0; nt < 4; nt++) bv[nt] = bias[bn + wn * 64 + nt * 16 + l15];
    #pragma unroll
    for (int mt = 0; mt < 4; mt++) {
        int r0 = bm + wm * 64 + mt * 16 + lq * 4;
        #pragma unroll
        for (int nt = 0; nt < 4; nt++) {
            int col = bn + wn * 64 + nt * 16 + l15;
            #pragma unroll
            for (int rr = 0; rr < 4; rr++)
                Cout[(size_t)(r0 + rr) * Dd + col] = acc[mt][nt][rr] + bv[nt];
        }
    }
}

// ---------------- MFMA flash attention v6: swapped QK^T (fp16), in-register P (T12) ----------------
// grid (B*H, S/256). 512 thr = 8 waves; wave owns 32 q-rows.
// sc = mfma32h(K, Q) -> lane holds S^T column (one q, 16 keys crow(r,hi) per half-wave).
// p = exp2(sc) (Q pre-scaled by log2e; masked keys give p=1 exactly, subtracted via cnt[b]).
// P -> bf16 A-fragments via cvt_pk + permlane32_swap; P/V stay bf16 (p needs exponent range).
__global__ __launch_bounds__(512, 4) void attn_mfma(
    u16* qctx, const u16* __restrict__ Kb, const u16* __restrict__ Vt,
    const float* __restrict__ maskf, const float* __restrict__ cntp)
{
    __shared__ u16 Ks[64][72];       // [key][d] fp16  (144B rows: 16B-aligned)
    __shared__ u16 Vs[64][72];       // [d][key] bf16
    __shared__ float li_s[8][32];    // per-wave li broadcast (epilogue only)
    const int tid = threadIdx.x, lane = tid & 63, wave = tid >> 6;
    const int l31 = lane & 31, hi = lane >> 5;
    const int bh = blockIdx.x, h = bh & 15, b = bh >> 4;
    const int q0 = blockIdx.y * 256;

    f16x8 qa[4];
    {
        const u16* qp = qctx + (size_t)(b * Ss + q0 + wave * 32 + l31) * Dd + h * 64 + hi * 8;
        #pragma unroll
        for (int kf = 0; kf < 4; kf++) qa[kf] = ldfragh(qp + kf * 16);
    }

    const int srow = tid >> 3, scol = (tid & 7) * 8;
    const u16* kgsrc = Kb + (size_t)(b * Ss + srow) * Dd + h * 64 + scol;
    const u16* vgsrc = Vt + (size_t)((b * Hh + h) * 64 + srow) * Ss + scol;
    u16* kdst = &Ks[srow][scol];
    u16* vdst = &Vs[srow][scol];

    f32x16 acc0 = {}, acc1 = {};
    float li = 0.f;

    uint4 kreg = *(const uint4*)kgsrc;
    uint4 vreg = *(const uint4*)vgsrc;

    for (int k0 = 0; k0 < Ss; k0 += 64) {
        __syncthreads();
        *(uint4*)kdst = kreg;
        *(uint4*)vdst = vreg;
        __syncthreads();
        int k0n = (k0 + 64 < Ss) ? k0 + 64 : 0;
        kreg = *(const uint4*)(kgsrc + (size_t)k0n * Dd);
        vreg = *(const uint4*)(vgsrc + k0n);

        #pragma unroll
        for (int nt = 0; nt < 2; nt++) {
            // QK^T swapped: A=K rows (32 keys), B=Q cols (32 q). Lane: q=l31, key=crow(r,hi).
            f32x16 sc = {};
            #pragma unroll
            for (int kf = 0; kf < 4; kf++) {
                f16x8 kb = ldfragh(&Ks[nt * 32 + l31][kf * 16 + hi * 8]);
                sc = mfma32h(kb, qa[kf], sc);
            }
            // keys 0..15 of this half -> pa0 -> PV kf=0
            float p[16];
            #pragma unroll
            for (int r = 0; r < 8; r++) p[r] = __builtin_amdgcn_exp2f(sc[r]);
            li += ((p[0] + p[1]) + (p[2] + p[3])) + ((p[4] + p[5]) + (p[6] + p[7]));
            {
                unsigned w0 = cvt_pk_bf16(p[0], p[1]), w1 = cvt_pk_bf16(p[2], p[3]);
                unsigned w2 = cvt_pk_bf16(p[4], p[5]), w3 = cvt_pk_bf16(p[6], p[7]);
                auto s02 = __builtin_amdgcn_permlane32_swap((int)w0, (int)w2, false, false);
                auto s13 = __builtin_amdgcn_permlane32_swap((int)w1, (int)w3, false, false);
                u32x4 pw = { (unsigned)s02[0], (unsigned)s13[0], (unsigned)s02[1], (unsigned)s13[1] };
                bf16x8 pa0 = __builtin_bit_cast(bf16x8, pw);
                bf16x8 v00 = ldfrag(&Vs[l31][nt * 32 + hi * 8]);
                bf16x8 v10 = ldfrag(&Vs[32 + l31][nt * 32 + hi * 8]);
                acc0 = mfma32(pa0, v00, acc0);
                acc1 = mfma32(pa0, v10, acc1);
            }
            // keys 16..31 -> pa1 -> PV kf=1
            #pragma unroll
            for (int r = 8; r < 16; r++) p[r] = __builtin_amdgcn_exp2f(sc[r]);
            li += ((p[8] + p[9]) + (p[10] + p[11])) + ((p[12] + p[13]) + (p[14] + p[15]));
            {
                unsigned w4 = cvt_pk_bf16(p[8], p[9]),  w5 = cvt_pk_bf16(p[10], p[11]);
                unsigned w6 = cvt_pk_bf16(p[12], p[13]), w7 = cvt_pk_bf16(p[14], p[15]);
                auto s46 = __builtin_amdgcn_permlane32_swap((int)w4, (int)w6, false, false);
                auto s57 = __builtin_amdgcn_permlane32_swap((int)w5, (int)w7, false, false);
                u32x4 pw = { (unsigned)s46[0], (unsigned)s57[0], (unsigned)s46[1], (unsigned)s57[1] };
                bf16x8 pa1 = __builtin_bit_cast(bf16x8, pw);
                bf16x8 v01 = ldfrag(&Vs[l31][nt * 32 + 16 + hi * 8]);
                bf16x8 v11 = ldfrag(&Vs[32 + l31][nt * 32 + 16 + hi * 8]);
                acc0 = mfma32(pa1, v01, acc0);
                acc1 = mfma32(pa1, v11, acc1);
            }
        }
    }

    // li is per-q (q = l31); combine complementary key-halves, broadcast to row lanes.
    float li_tot = li + __shfl_xor(li, 32);
    if (hi == 0) li_s[wave][l31] = li_tot;
    __builtin_amdgcn_s_barrier();
    float cntb = cntp[b];
    #pragma unroll
    for (int g = 0; g < 4; g++) {
        float4 lv = *(const float4*)&li_s[wave][g * 8 + hi * 4];
        #pragma unroll
        for (int j = 0; j < 4; j++) {
            int r = g * 4 + j;
            int row = j + 8 * g + 4 * hi;
            int q = q0 + wave * 32 + row;
            float qm = maskf[b * Ss + q];
            float den = lv[j] - cntb;                 // subtract masked keys' exact 1.0s
            float rl = den > 0.f ? qm / den : 0.f;
            u16* op = qctx + (size_t)(b * Ss + q) * Dd + h * 64 + l31;
            op[0]  = f2bf(acc0[r] * rl);
            op[32] = f2bf(acc1[r] * rl);
        }
    }
}

extern "C" void kernel_launch(void* const* d_in, const int* in_sizes, int n_in,
                              void* d_out, int out_size, void* d_ws, size_t ws_size,
                              hipStream_t stream) {
    const float* X  = (const float*)d_in[0];
    const unsigned char* mr = (const unsigned char*)d_in[1];
    const float* Wq = (const float*)d_in[2];
    const float* bq = (const float*)d_in[3];
    const float* Wk = (const float*)d_in[4];
    const float* bk = (const float*)d_in[5];
    const float* Wv = (const float*)d_in[6];
    const float* bv = (const float*)d_in[7];
    const float* Wo = (const float*)d_in[8];
    const float* bo = (const float*)d_in[9];
    float* out = (float*)d_out;

    // ws (64 MB)
    u16* wsb = (u16*)d_ws;
    u16* Xh  = wsb;                // fp16 X; dies after QKV-gemm; Wo^T overlays
    u16* Qb  = wsb + (size_t)SZt;  // fp16 Q; ctx (bf16) aliases after attention
    u16* Kb  = wsb + 2 * (size_t)SZt;   // fp16 K
    u16* Vt  = wsb + 3 * (size_t)SZt;   // bf16 V^T
    u16* Wot = Xh;
    // d_out scratch (all dead before gemm_out writes d_out)
    u16* ob  = (u16*)d_out;
    u16* Wcat = ob + (size_t)SZt;              // fp16 Wqt|Wkt|Wvt contiguous = [3072][1024]
    u16* Wqt = Wcat;
    u16* Wkt = Wqt + 1048576;
    u16* Wvt = Wkt + 1048576;
    float* mnorm = (float*)(Wvt + 1048576);    // 32 KB
    float* bcat  = mnorm + Bb * Ss;            // 12 KB
    float* cntp  = bcat + 3072;                // 16 B (per-batch masked-key count)

    dim3 tg(32, 32), tb(32, 8);

    normalize_mask<<<1, 1024, 0, stream>>>(mr, mnorm, cntp, Bb * Ss);
    concat_bias<<<12, 256, 0, stream>>>(bq, bk, bv, bcat);
    convert_xh<<<SZt / 1024, 256, 0, stream>>>(X, Xh);
    transpose_wh<<<tg, tb, 0, stream>>>(Wq, Wqt);
    transpose_wh<<<tg, tb, 0, stream>>>(Wk, Wkt);
    transpose_wh<<<tg, tb, 0, stream>>>(Wv, Wvt);
    gemm_qkv<<<dim3(24, 64), 256, 0, stream>>>(Xh, Wcat, bcat, mnorm, Qb, Kb, Vt);
    transpose_w<<<tg, tb, 0, stream>>>(Wo, Wot);               // Xh dead -> reuse (bf16 for gemm_out)
    attn_mfma<<<dim3(Bb * Hh, Ss / 256), 512, 0, stream>>>(Qb, Kb, Vt, mnorm, cntp);
    gemm_out<<<dim3(8, 64), 256, 0, stream>>>(Qb, Wot, bo, out);
}

// Round 5
// 293.789 us; speedup vs baseline: 1.1610x; 1.0584x over previous
//
#include <hip/hip_runtime.h>

// B=4, S=2048, D=1024, H=16, head_dim=64. Inputs fp32, output fp32.
// Round 14/15: GEMMs as deep-pipelined 256x128 tiles (T3+T4+T2):
//  - 512 thr / 8 waves (4M x 2N), BK=64, per-wave 64x64 out (acc[4][4]).
//  - A triple-buffered, B double-buffered in LDS (128 KiB total, 1 block/CU).
//  - counted s_waitcnt vmcnt(4) + raw s_barrier: loads stay in flight across
//    barriers (never drain to 0 in-loop), 2-iteration landing window.
//  - T2 XOR swizzle both-sides: global source col pre-swizzled (rule #21),
//    ds_read col ^ ((row&7)*8) -> 16-way bank conflict eliminated.
// attn_mfma (T12 in-register softmax) unchanged from round 13.
// Round 15 = round 14 resubmit (bench infra failed; kernel never ran).
// ws (64MB): Xh[16] | Qb/ctx[16] | Kb[16] | Vt[16]  (Wo^T overlays Xh)
// d_out (32MB) pre-final scratch: Wcat[6] | mnorm[32KB] | bcat[12KB] | cnt[4]

#define Bb 4
#define Ss 2048
#define Dd 1024
#define Hh 16
#define SZt 8388608

typedef short bf16x8 __attribute__((ext_vector_type(8)));
typedef _Float16 f16x8 __attribute__((ext_vector_type(8)));
typedef float f32x4 __attribute__((ext_vector_type(4)));
typedef float f32x16 __attribute__((ext_vector_type(16)));
typedef unsigned int u32x4 __attribute__((ext_vector_type(4)));
typedef unsigned short u16;

__device__ __forceinline__ float bf2f(u16 u) {
    return __builtin_bit_cast(float, ((unsigned)u) << 16);
}
__device__ __forceinline__ u16 f2bf(float f) {
    unsigned u = __builtin_bit_cast(unsigned, f);
    unsigned r = 0x7FFFu + ((u >> 16) & 1u);
    return (u16)((u + r) >> 16);
}
__device__ __forceinline__ u16 f2h(float f) {
    _Float16 h = (_Float16)f;
    return __builtin_bit_cast(u16, h);
}
__device__ __forceinline__ bf16x8 ldfrag(const u16* p) {
    return __builtin_bit_cast(bf16x8, *(const uint4*)p);
}
__device__ __forceinline__ f16x8 ldfragh(const u16* p) {
    return __builtin_bit_cast(f16x8, *(const uint4*)p);
}
__device__ __forceinline__ f32x4 mfma16h(f16x8 a, f16x8 b, f32x4 c) {
    return __builtin_amdgcn_mfma_f32_16x16x32_f16(a, b, c, 0, 0, 0);
}
__device__ __forceinline__ f32x4 mfma16b(bf16x8 a, bf16x8 b, f32x4 c) {
    return __builtin_amdgcn_mfma_f32_16x16x32_bf16(a, b, c, 0, 0, 0);
}
__device__ __forceinline__ f32x16 mfma32(bf16x8 a, bf16x8 b, f32x16 c) {
    return __builtin_amdgcn_mfma_f32_32x32x16_bf16(a, b, c, 0, 0, 0);
}
__device__ __forceinline__ f32x16 mfma32h(f16x8 a, f16x8 b, f32x16 c) {
    return __builtin_amdgcn_mfma_f32_32x32x16_f16(a, b, c, 0, 0, 0);
}
// pack two f32 -> one u32 of 2x bf16 (lo=a, hi=b); no builtin on gfx950 (T12 recipe)
__device__ __forceinline__ unsigned cvt_pk_bf16(float a, float b) {
    unsigned r;
    asm("v_cvt_pk_bf16_f32 %0, %1, %2" : "=v"(r) : "v"(a), "v"(b));
    return r;
}
// async global->LDS, 16B/lane; LDS dest = wave-uniform base + lane*16 (m97 contract)
__device__ __forceinline__ void gl2lds16(const u16* g, u16* l) {
    __builtin_amdgcn_global_load_lds(
        (const __attribute__((address_space(1))) u16*)g,
        (__attribute__((address_space(3))) u16*)l, 16, 0, 0);
}

// ---------------- mask normalization -> mnorm (0/1 float) + per-batch masked count ----------------
__global__ void normalize_mask(const unsigned char* __restrict__ raw, float* __restrict__ out,
                               float* __restrict__ cnt, int n) {
    __shared__ int flags;
    __shared__ float scnt[Bb];
    if (threadIdx.x == 0) flags = 0;
    if (threadIdx.x < Bb) scnt[threadIdx.x] = 0.f;
    __syncthreads();
    int f = 0;
    for (int i = threadIdx.x; i < n; i += blockDim.x) {
        unsigned char c = raw[i];
        if ((i & 3) != 0 && c) f |= 1;
        if ((i & 3) == 1 && c >= 2) f |= 2;
        if ((i & 3) == 3 && c >= 2) f |= 4;
    }
    if (f) atomicOr(&flags, f);
    __syncthreads();
    int fl = flags;
    int layout;                 // 0=int32, 1=u8, 2=bf16, 3=f32
    if (!(fl & 1)) layout = 0;
    else if (fl & 2) layout = 2;
    else if (fl & 4) layout = 3;
    else layout = 1;
    for (int i = threadIdx.x; i < n; i += blockDim.x) {
        int v;
        if (layout == 0)      v = ((const int*)raw)[i];
        else if (layout == 1) v = raw[i];
        else if (layout == 2) v = ((const u16*)raw)[i] != 0;
        else                  v = ((const unsigned*)raw)[i] != 0;
        out[i] = (v != 0) ? 1.0f : 0.0f;
        if (v == 0) atomicAdd(&scnt[i >> 11], 1.0f);   // i>>11 = batch index (S=2048)
    }
    __syncthreads();
    if (threadIdx.x < Bb) cnt[threadIdx.x] = scnt[threadIdx.x];
}

// ---------------- bias concat [bq|bk|bv] -> bcat[3072] ----------------
__global__ void concat_bias(const float* __restrict__ a, const float* __restrict__ b,
                            const float* __restrict__ c, float* __restrict__ o) {
    int i = blockIdx.x * 256 + threadIdx.x;
    o[i] = (i < 1024) ? a[i] : ((i < 2048) ? b[i - 1024] : c[i - 2048]);
}

// ---------------- X fp32 -> fp16 ----------------
__global__ __launch_bounds__(256) void convert_xh(const float* __restrict__ X,
                                                  u16* __restrict__ Xh) {
    size_t i = ((size_t)blockIdx.x * 256 + threadIdx.x) * 4;
    float4 v = *(const float4*)(X + i);
    u16 h0 = f2h(v.x), h1 = f2h(v.y), h2 = f2h(v.z), h3 = f2h(v.w);
    uint2 ph = { (unsigned)h0 | ((unsigned)h1 << 16), (unsigned)h2 | ((unsigned)h3 << 16) };
    *(uint2*)(Xh + i) = ph;
}

// ---------------- W [K][N] fp32 -> Wt [N][K] (tiled transpose) ----------------
__global__ __launch_bounds__(256) void transpose_wh(const float* __restrict__ W, u16* __restrict__ Wt) {
    __shared__ float t[32][33];
    const int tx = threadIdx.x, ty = threadIdx.y;
    const int n0 = blockIdx.x * 32, k0 = blockIdx.y * 32;
    #pragma unroll
    for (int i = 0; i < 4; i++)
        t[ty + i * 8][tx] = W[(size_t)(k0 + ty + i * 8) * Dd + n0 + tx];
    __syncthreads();
    #pragma unroll
    for (int i = 0; i < 4; i++)
        Wt[(size_t)(n0 + ty + i * 8) * Dd + k0 + tx] = f2h(t[tx][ty + i * 8]);
}
__global__ __launch_bounds__(256) void transpose_w(const float* __restrict__ W, u16* __restrict__ Wt) {
    __shared__ float t[32][33];
    const int tx = threadIdx.x, ty = threadIdx.y;
    const int n0 = blockIdx.x * 32, k0 = blockIdx.y * 32;
    #pragma unroll
    for (int i = 0; i < 4; i++)
        t[ty + i * 8][tx] = W[(size_t)(k0 + ty + i * 8) * Dd + n0 + tx];
    __syncthreads();
    #pragma unroll
    for (int i = 0; i < 4; i++)
        Wt[(size_t)(n0 + ty + i * 8) * Dd + k0 + tx] = f2bf(t[tx][ty + i * 8]);
}

// ---------------- fused QKV GEMM (fp16, pipelined 256x128): [Q|K|V] = X @ Wcat^T + bcat ----
// Epilogue: Q scaled by LOG2E, stored fp16; K masked fp16; V masked bf16 [b][h][d][s].
__global__ __launch_bounds__(512, 2) void gemm_qkv(
    const u16* __restrict__ Ah, const u16* __restrict__ Wcat, const float* __restrict__ bcat,
    const float* __restrict__ mnorm,
    u16* __restrict__ Qb, u16* __restrict__ Kb, u16* __restrict__ Vt)
{
    __shared__ u16 As[3][256][64];   // 96 KiB, triple-buffered
    __shared__ u16 Bs[2][128][64];   // 32 KiB, double-buffered
    const int tid = threadIdx.x, lane = tid & 63, wave = tid >> 6;
    const int wm = wave >> 1, wn = wave & 1;
    const int bm = blockIdx.y * 256, bn = blockIdx.x * 128;
    const bool isQ = (bn < 1024);
    const int l15 = lane & 15, lq = lane >> 4;
    const int rl = lane >> 3;                       // row-in-chunk 0..7
    const int s8 = ((lane & 7) ^ rl) * 8;           // T2 pre-swizzled source slot (u16 units)
    const u16* agp = Ah + (size_t)(bm + wave * 32 + rl) * Dd + s8;
    const u16* bgp = Wcat + (size_t)(bn + wave * 16 + rl) * Dd + s8;

    f32x4 acc[4][4] = {};

    auto stageA = [&](int slot, int kt) {
        u16* d = &As[slot][wave * 32][0];           // wave-uniform dest
        const u16* g = agp + kt * 64;
        #pragma unroll
        for (int j = 0; j < 4; ++j)
            gl2lds16(g + (size_t)(j * 8) * Dd, d + j * 8 * 64);
    };
    auto stageB = [&](int slot, int kt) {
        u16* d = &Bs[slot][wave * 16][0];
        const u16* g = bgp + kt * 64;
        #pragma unroll
        for (int j = 0; j < 2; ++j)
            gl2lds16(g + (size_t)(j * 8) * Dd, d + j * 8 * 64);
    };

    // prologue: A0(4), B0(2), A1(4) -> wait until only A1 outstanding
    stageA(0, 0); stageB(0, 0); stageA(1, 1);
    asm volatile("s_waitcnt vmcnt(4)" ::: "memory");
    __builtin_amdgcn_s_barrier();

    int cs = 0;                                     // compute slot for A
    for (int t = 0; t < 16; ++t) {
        if (t < 15) stageB((t + 1) & 1, t + 1);
        if (t < 14) { int ss = (cs >= 1) ? cs - 1 : cs + 2; stageA(ss, t + 2); }
        #pragma unroll
        for (int kf = 0; kf < 2; kf++) {
            f16x8 b[4], a[4];
            #pragma unroll
            for (int nt = 0; nt < 4; nt++)
                b[nt] = ldfragh(&Bs[t & 1][wn * 64 + nt * 16 + l15][(kf * 32 + lq * 8) ^ ((l15 & 7) * 8)]);
            #pragma unroll
            for (int mt = 0; mt < 4; mt++)
                a[mt] = ldfragh(&As[cs][wm * 64 + mt * 16 + l15][(kf * 32 + lq * 8) ^ ((l15 & 7) * 8)]);
            #pragma unroll
            for (int mt = 0; mt < 4; mt++)
                #pragma unroll
                for (int nt = 0; nt < 4; nt++)
                    acc[mt][nt] = mfma16h(a[mt], b[nt], acc[mt][nt]);
        }
        // counted drain: oldest {A(t+1), B(t+1)} done; {A(t+2)} stays in flight
        if (t < 14)       asm volatile("s_waitcnt vmcnt(4)" ::: "memory");
        else if (t == 14) asm volatile("s_waitcnt vmcnt(0)" ::: "memory");
        if (t < 15) __builtin_amdgcn_s_barrier();
        cs = (cs >= 2) ? 0 : cs + 1;
    }

    const float LOG2E = 1.44269504088896f;
    float bv[4];
    #pragma unroll
    for (int nt = 0; nt < 4; nt++) bv[nt] = bcat[bn + wn * 64 + nt * 16 + l15];
    #pragma unroll
    for (int mt = 0; mt < 4; mt++) {
        int r0 = bm + wm * 64 + mt * 16 + lq * 4;
        float mk[4];
        if (!isQ) {
            #pragma unroll
            for (int rr = 0; rr < 4; rr++) mk[rr] = mnorm[r0 + rr];
        }
        #pragma unroll
        for (int nt = 0; nt < 4; nt++) {
            int col = bn + wn * 64 + nt * 16 + l15;
            if (col < 1024) {                                  // Q fp16 (pre-scaled by log2e)
                #pragma unroll
                for (int rr = 0; rr < 4; rr++)
                    Qb[(size_t)(r0 + rr) * Dd + col] = f2h((acc[mt][nt][rr] + bv[nt]) * LOG2E);
            } else if (col < 2048) {                           // K fp16 (masked rows -> 0)
                int c2 = col - 1024;
                #pragma unroll
                for (int rr = 0; rr < 4; rr++)
                    Kb[(size_t)(r0 + rr) * Dd + c2] = f2h((acc[mt][nt][rr] + bv[nt]) * mk[rr]);
            } else {                                           // V bf16, transposed [b][h][d][s], masked
                int c2 = col - 2048;
                int hh = c2 >> 6, dd = c2 & 63, b_ = r0 >> 11, s0 = r0 & 2047;
                u16 e0 = f2bf((acc[mt][nt][0] + bv[nt]) * mk[0]);
                u16 e1 = f2bf((acc[mt][nt][1] + bv[nt]) * mk[1]);
                u16 e2 = f2bf((acc[mt][nt][2] + bv[nt]) * mk[2]);
                u16 e3 = f2bf((acc[mt][nt][3] + bv[nt]) * mk[3]);
                uint2 pk = { (unsigned)e0 | ((unsigned)e1 << 16), (unsigned)e2 | ((unsigned)e3 << 16) };
                *(uint2*)(Vt + (size_t)((b_ * Hh + hh) * 64 + dd) * Ss + s0) = pk;
            }
        }
    }
}

// ---------------- output projection (bf16, pipelined 256x128): fp32 out ----------------
__global__ __launch_bounds__(512, 2) void gemm_out(
    const u16* __restrict__ Ah, const u16* __restrict__ Wt,
    const float* __restrict__ bias, float* __restrict__ Cout)
{
    __shared__ u16 As[3][256][64];
    __shared__ u16 Bs[2][128][64];
    const int tid = threadIdx.x, lane = tid & 63, wave = tid >> 6;
    const int wm = wave >> 1, wn = wave & 1;
    const int bm = blockIdx.y * 256, bn = blockIdx.x * 128;
    const int l15 = lane & 15, lq = lane >> 4;
    const int rl = lane >> 3;
    const int s8 = ((lane & 7) ^ rl) * 8;
    const u16* agp = Ah + (size_t)(bm + wave * 32 + rl) * Dd + s8;
    const u16* bgp = Wt + (size_t)(bn + wave * 16 + rl) * Dd + s8;

    f32x4 acc[4][4] = {};

    auto stageA = [&](int slot, int kt) {
        u16* d = &As[slot][wave * 32][0];
        const u16* g = agp + kt * 64;
        #pragma unroll
        for (int j = 0; j < 4; ++j)
            gl2lds16(g + (size_t)(j * 8) * Dd, d + j * 8 * 64);
    };
    auto stageB = [&](int slot, int kt) {
        u16* d = &Bs[slot][wave * 16][0];
        const u16* g = bgp + kt * 64;
        #pragma unroll
        for (int j = 0; j < 2; ++j)
            gl2lds16(g + (size_t)(j * 8) * Dd, d + j * 8 * 64);
    };

    stageA(0, 0); stageB(0, 0); stageA(1, 1);
    asm volatile("s_waitcnt vmcnt(4)" ::: "memory");
    __builtin_amdgcn_s_barrier();

    int cs = 0;
    for (int t = 0; t < 16; ++t) {
        if (t < 15) stageB((t + 1) & 1, t + 1);
        if (t < 14) { int ss = (cs >= 1) ? cs - 1 : cs + 2; stageA(ss, t + 2); }
        #pragma unroll
        for (int kf = 0; kf < 2; kf++) {
            bf16x8 b[4], a[4];
            #pragma unroll
            for (int nt = 0; nt < 4; nt++)
                b[nt] = ldfrag(&Bs[t & 1][wn * 64 + nt * 16 + l15][(kf * 32 + lq * 8) ^ ((l15 & 7) * 8)]);
            #pragma unroll
            for (int mt = 0; mt < 4; mt++)
                a[mt] = ldfrag(&As[cs][wm * 64 + mt * 16 + l15][(kf * 32 + lq * 8) ^ ((l15 & 7) * 8)]);
            #pragma unroll
            for (int mt = 0; mt < 4; mt++)
                #pragma unroll
                for (int nt = 0; nt < 4; nt++)
                    acc[mt][nt] = mfma16b(a[mt], b[nt], acc[mt][nt]);
        }
        if (t < 14)       asm volatile("s_waitcnt vmcnt(4)" ::: "memory");
        else if (t == 14) asm volatile("s_waitcnt vmcnt(0)" ::: "memory");
        if (t < 15) __builtin_amdgcn_s_barrier();
        cs = (cs >= 2) ? 0 : cs + 1;
    }

    float bv[4];
    #pragma unroll
    for (int nt = 0; nt < 4; nt++) bv[nt] = bias[bn + wn * 64 + nt * 16 + l15];
    #pragma unroll
    for (int mt = 0; mt < 4; mt++) {
        int r0 = bm + wm * 64 + mt * 16 + lq * 4;
        #pragma unroll
        for (int nt = 0; nt < 4; nt++) {
            int col = bn + wn * 64 + nt * 16 + l15;
            #pragma unroll
            for (int rr = 0; rr < 4; rr++)
                Cout[(size_t)(r0 + rr) * Dd + col] = acc[mt][nt][rr] + bv[nt];
        }
    }
}

// ---------------- MFMA flash attention v6: swapped QK^T (fp16), in-register P (T12) ----------------
__global__ __launch_bounds__(512, 4) void attn_mfma(
    u16* qctx, const u16* __restrict__ Kb, const u16* __restrict__ Vt,
    const float* __restrict__ maskf, const float* __restrict__ cntp)
{
    __shared__ u16 Ks[64][72];       // [key][d] fp16  (144B rows: 16B-aligned)
    __shared__ u16 Vs[64][72];       // [d][key] bf16
    __shared__ float li_s[8][32];    // per-wave li broadcast (epilogue only)
    const int tid = threadIdx.x, lane = tid & 63, wave = tid >> 6;
    const int l31 = lane & 31, hi = lane >> 5;
    const int bh = blockIdx.x, h = bh & 15, b = bh >> 4;
    const int q0 = blockIdx.y * 256;

    f16x8 qa[4];
    {
        const u16* qp = qctx + (size_t)(b * Ss + q0 + wave * 32 + l31) * Dd + h * 64 + hi * 8;
        #pragma unroll
        for (int kf = 0; kf < 4; kf++) qa[kf] = ldfragh(qp + kf * 16);
    }

    const int srow = tid >> 3, scol = (tid & 7) * 8;
    const u16* kgsrc = Kb + (size_t)(b * Ss + srow) * Dd + h * 64 + scol;
    const u16* vgsrc = Vt + (size_t)((b * Hh + h) * 64 + srow) * Ss + scol;
    u16* kdst = &Ks[srow][scol];
    u16* vdst = &Vs[srow][scol];

    f32x16 acc0 = {}, acc1 = {};
    float li = 0.f;

    uint4 kreg = *(const uint4*)kgsrc;
    uint4 vreg = *(const uint4*)vgsrc;

    for (int k0 = 0; k0 < Ss; k0 += 64) {
        __syncthreads();
        *(uint4*)kdst = kreg;
        *(uint4*)vdst = vreg;
        __syncthreads();
        int k0n = (k0 + 64 < Ss) ? k0 + 64 : 0;
        kreg = *(const uint4*)(kgsrc + (size_t)k0n * Dd);
        vreg = *(const uint4*)(vgsrc + k0n);

        #pragma unroll
        for (int nt = 0; nt < 2; nt++) {
            f32x16 sc = {};
            #pragma unroll
            for (int kf = 0; kf < 4; kf++) {
                f16x8 kb = ldfragh(&Ks[nt * 32 + l31][kf * 16 + hi * 8]);
                sc = mfma32h(kb, qa[kf], sc);
            }
            float p[16];
            #pragma unroll
            for (int r = 0; r < 8; r++) p[r] = __builtin_amdgcn_exp2f(sc[r]);
            li += ((p[0] + p[1]) + (p[2] + p[3])) + ((p[4] + p[5]) + (p[6] + p[7]));
            {
                unsigned w0 = cvt_pk_bf16(p[0], p[1]), w1 = cvt_pk_bf16(p[2], p[3]);
                unsigned w2 = cvt_pk_bf16(p[4], p[5]), w3 = cvt_pk_bf16(p[6], p[7]);
                auto s02 = __builtin_amdgcn_permlane32_swap((int)w0, (int)w2, false, false);
                auto s13 = __builtin_amdgcn_permlane32_swap((int)w1, (int)w3, false, false);
                u32x4 pw = { (unsigned)s02[0], (unsigned)s13[0], (unsigned)s02[1], (unsigned)s13[1] };
                bf16x8 pa0 = __builtin_bit_cast(bf16x8, pw);
                bf16x8 v00 = ldfrag(&Vs[l31][nt * 32 + hi * 8]);
                bf16x8 v10 = ldfrag(&Vs[32 + l31][nt * 32 + hi * 8]);
                acc0 = mfma32(pa0, v00, acc0);
                acc1 = mfma32(pa0, v10, acc1);
            }
            #pragma unroll
            for (int r = 8; r < 16; r++) p[r] = __builtin_amdgcn_exp2f(sc[r]);
            li += ((p[8] + p[9]) + (p[10] + p[11])) + ((p[12] + p[13]) + (p[14] + p[15]));
            {
                unsigned w4 = cvt_pk_bf16(p[8], p[9]),  w5 = cvt_pk_bf16(p[10], p[11]);
                unsigned w6 = cvt_pk_bf16(p[12], p[13]), w7 = cvt_pk_bf16(p[14], p[15]);
                auto s46 = __builtin_amdgcn_permlane32_swap((int)w4, (int)w6, false, false);
                auto s57 = __builtin_amdgcn_permlane32_swap((int)w5, (int)w7, false, false);
                u32x4 pw = { (unsigned)s46[0], (unsigned)s57[0], (unsigned)s46[1], (unsigned)s57[1] };
                bf16x8 pa1 = __builtin_bit_cast(bf16x8, pw);
                bf16x8 v01 = ldfrag(&Vs[l31][nt * 32 + 16 + hi * 8]);
                bf16x8 v11 = ldfrag(&Vs[32 + l31][nt * 32 + 16 + hi * 8]);
                acc0 = mfma32(pa1, v01, acc0);
                acc1 = mfma32(pa1, v11, acc1);
            }
        }
    }

    float li_tot = li + __shfl_xor(li, 32);
    if (hi == 0) li_s[wave][l31] = li_tot;
    __builtin_amdgcn_s_barrier();
    float cntb = cntp[b];
    #pragma unroll
    for (int g = 0; g < 4; g++) {
        float4 lv = *(const float4*)&li_s[wave][g * 8 + hi * 4];
        #pragma unroll
        for (int j = 0; j < 4; j++) {
            int r = g * 4 + j;
            int row = j + 8 * g + 4 * hi;
            int q = q0 + wave * 32 + row;
            float qm = maskf[b * Ss + q];
            float den = lv[j] - cntb;
            float rl = den > 0.f ? qm / den : 0.f;
            u16* op = qctx + (size_t)(b * Ss + q) * Dd + h * 64 + l31;
            op[0]  = f2bf(acc0[r] * rl);
            op[32] = f2bf(acc1[r] * rl);
        }
    }
}

extern "C" void kernel_launch(void* const* d_in, const int* in_sizes, int n_in,
                              void* d_out, int out_size, void* d_ws, size_t ws_size,
                              hipStream_t stream) {
    const float* X  = (const float*)d_in[0];
    const unsigned char* mr = (const unsigned char*)d_in[1];
    const float* Wq = (const float*)d_in[2];
    const float* bq = (const float*)d_in[3];
    const float* Wk = (const float*)d_in[4];
    const float* bk = (const float*)d_in[5];
    const float* Wv = (const float*)d_in[6];
    const float* bv = (const float*)d_in[7];
    const float* Wo = (const float*)d_in[8];
    const float* bo = (const float*)d_in[9];
    float* out = (float*)d_out;

    // ws (64 MB)
    u16* wsb = (u16*)d_ws;
    u16* Xh  = wsb;                // fp16 X; dies after QKV-gemm; Wo^T overlays
    u16* Qb  = wsb + (size_t)SZt;  // fp16 Q; ctx (bf16) aliases after attention
    u16* Kb  = wsb + 2 * (size_t)SZt;   // fp16 K
    u16* Vt  = wsb + 3 * (size_t)SZt;   // bf16 V^T
    u16* Wot = Xh;
    // d_out scratch (all dead before gemm_out writes d_out)
    u16* ob  = (u16*)d_out;
    u16* Wcat = ob + (size_t)SZt;              // fp16 Wqt|Wkt|Wvt contiguous = [3072][1024]
    u16* Wqt = Wcat;
    u16* Wkt = Wqt + 1048576;
    u16* Wvt = Wkt + 1048576;
    float* mnorm = (float*)(Wvt + 1048576);    // 32 KB
    float* bcat  = mnorm + Bb * Ss;            // 12 KB
    float* cntp  = bcat + 3072;                // 16 B (per-batch masked-key count)

    dim3 tg(32, 32), tb(32, 8);

    normalize_mask<<<1, 1024, 0, stream>>>(mr, mnorm, cntp, Bb * Ss);
    concat_bias<<<12, 256, 0, stream>>>(bq, bk, bv, bcat);
    convert_xh<<<SZt / 1024, 256, 0, stream>>>(X, Xh);
    transpose_wh<<<tg, tb, 0, stream>>>(Wq, Wqt);
    transpose_wh<<<tg, tb, 0, stream>>>(Wk, Wkt);
    transpose_wh<<<tg, tb, 0, stream>>>(Wv, Wvt);
    gemm_qkv<<<dim3(24, 32), 512, 0, stream>>>(Xh, Wcat, bcat, mnorm, Qb, Kb, Vt);
    transpose_w<<<tg, tb, 0, stream>>>(Wo, Wot);               // Xh dead -> reuse (bf16 for gemm_out)
    attn_mfma<<<dim3(Bb * Hh, Ss / 256), 512, 0, stream>>>(Qb, Kb, Vt, mnorm, cntp);
    gemm_out<<<dim3(8, 32), 512, 0, stream>>>(Qb, Wot, bo, out);
}